// Round 16
// baseline (430.667 us; speedup 1.0000x reference)
//
#include <hip/hip_runtime.h>
#include <cstddef>

#define N_NODES 100000
#define N_PAD   100032          // padded to 64-row multiple
#define N_EDGES 1600000
#define DIM 128
#define LN_EPS 1e-5f
#define ZROW   N_NODES          // dedicated all-zero feature row
#define COL_CAP 3200000         // >= E + 15*N (padded adjacency cap)

#define B_SHIFT 9
#define B_SIZE  512
#define N_BKT   196             // ceil(100032/512)
#define SEGCAP  10240           // per-bucket pair segment (mean 8163, ~23 sigma headroom)
#define EPB     4096            // edges per block in scatter pass
#define NBLK    ((N_EDGES + EPB - 1) / EPB)   // 391

typedef short bf16x8 __attribute__((ext_vector_type(8)));
typedef float f32x4 __attribute__((ext_vector_type(4)));
typedef float f32x2 __attribute__((ext_vector_type(2)));

__device__ __forceinline__ float asf(uint u) {
    union { uint i; float f; } c; c.i = u; return c.f;
}
__device__ __forceinline__ float bf2f(uint u) { return asf(u << 16); }
__device__ __forceinline__ ushort f2bf(float x) {
    union { float f; uint i; } c; c.f = x;
    uint r = c.i + 0x7fffu + ((c.i >> 16) & 1u);   // RNE
    return (ushort)(r >> 16);
}

// unpack one dword (2 bf16) and accumulate into a float2 (v_pk_add_f32)
__device__ __forceinline__ void accp(f32x2* acc, uint p) {
    f32x2 v;
    v.x = asf(p << 16);
    v.y = asf(p & 0xffff0000u);
    *acc += v;
}
__device__ __forceinline__ void accq(f32x2* a, uint4 p) {
    accp(&a[0], p.x); accp(&a[1], p.y); accp(&a[2], p.z); accp(&a[3], p.w);
}

// ================= CSR build: segmented scatter (no pre-histogram) =================

__global__ __launch_bounds__(256) void bscatter_kernel(const int* __restrict__ src,
                                                       const int* __restrict__ dst,
                                                       int* __restrict__ gcur,
                                                       int2* __restrict__ pairs) {
    __shared__ int lcnt[N_BKT];
    __shared__ int lbase[N_BKT];
    const int tid = threadIdx.x;
    if (tid < N_BKT) lcnt[tid] = 0;
    __syncthreads();
    const int base = blockIdx.x * EPB;
    int ls[16], ld[16];
    #pragma unroll
    for (int k = 0; k < 16; ++k) {
        int t = base + tid + k * 256;
        if (t < N_EDGES) {
            ls[k] = src[t]; ld[k] = dst[t];
            atomicAdd(&lcnt[ld[k] >> B_SHIFT], 1);
        } else ld[k] = -1;
    }
    __syncthreads();
    if (tid < N_BKT) lbase[tid] = lcnt[tid] ? atomicAdd(&gcur[tid], lcnt[tid]) : 0;
    __syncthreads();
    if (tid < N_BKT) lcnt[tid] = 0;
    __syncthreads();
    #pragma unroll
    for (int k = 0; k < 16; ++k) {
        if (ld[k] >= 0) {
            int b = ld[k] >> B_SHIFT;
            int r = atomicAdd(&lcnt[b], 1);
            pairs[b * SEGCAP + lbase[b] + r] = make_int2(ls[k], ld[k]);
        }
    }
}

// per-bucket degree count -> PADDED (mult of 16) exclusive scan, bucket-local.
__global__ __launch_bounds__(256) void ndeg_kernel(const int2* __restrict__ pairs,
                                                   const int* __restrict__ gcur,
                                                   int* __restrict__ row_ptr,
                                                   int* __restrict__ bpad) {
    __shared__ int ldeg[B_SIZE];
    __shared__ int ws4[4];
    const int b = blockIdx.x;
    const int node0 = b << B_SHIFT;
    const int tid = threadIdx.x;
    ldeg[tid] = 0; ldeg[tid + 256] = 0;
    __syncthreads();
    const int beg = b * SEGCAP;
    const int end = beg + gcur[b];
    for (int t = beg + tid; t < end; t += 256)
        atomicAdd(&ldeg[pairs[t].y - node0], 1);
    __syncthreads();
    const int d0 = (ldeg[2 * tid] + 15) & ~15;        // padded degrees
    const int d1 = (ldeg[2 * tid + 1] + 15) & ~15;
    const int sum2 = d0 + d1;
    const int lane = tid & 63, wv = tid >> 6;
    int incl = sum2;
    #pragma unroll
    for (int off = 1; off < 64; off <<= 1) {
        int t = __shfl_up(incl, off);
        if (lane >= off) incl += t;
    }
    if (lane == 63) ws4[wv] = incl;
    __syncthreads();
    int woff = 0;
    if (wv > 0) woff += ws4[0];
    if (wv > 1) woff += ws4[1];
    if (wv > 2) woff += ws4[2];
    const int e0 = woff + incl - sum2;                // bucket-local padded start
    const int n0 = node0 + 2 * tid;
    if (n0 < N_NODES)     row_ptr[n0]     = e0;
    if (n0 + 1 < N_NODES) row_ptr[n0 + 1] = e0 + d0;
    if (tid == 255) bpad[b] = woff + incl;            // bucket total
}

// scan of 196 bucket padded totals
__global__ __launch_bounds__(256) void pscan_kernel(const int* __restrict__ bpad,
                                                    int* __restrict__ bpadstart) {
    __shared__ int s[256];
    const int tid = threadIdx.x;
    int v = (tid < N_BKT) ? bpad[tid] : 0;
    s[tid] = v;
    __syncthreads();
    for (int off = 1; off < 256; off <<= 1) {
        int t = (tid >= off) ? s[tid - off] : 0;
        __syncthreads();
        s[tid] += t;
        __syncthreads();
    }
    if (tid < N_BKT) bpadstart[tid] = s[tid] - v;
    if (tid == N_BKT - 1) bpadstart[N_BKT] = s[tid];
}

// make row_ptr absolute; pad rows [N_NODES..N_PAD] get degree 0
__global__ void addbase_kernel(int* __restrict__ row_ptr, const int* __restrict__ bpadstart) {
    int n = blockIdx.x * 256 + threadIdx.x;
    if (n < N_NODES) row_ptr[n] += bpadstart[n >> B_SHIFT];
    else if (n <= N_PAD) row_ptr[n] = bpadstart[N_BKT];
}

// fill CSR + pad each node's slot tail with ZROW
__global__ __launch_bounds__(256) void bfill_kernel(const int2* __restrict__ pairs,
                                                    const int* __restrict__ gcur,
                                                    const int* __restrict__ row_ptr,
                                                    int* __restrict__ col) {
    __shared__ int lcur[B_SIZE];
    const int b = blockIdx.x;
    const int node0 = b << B_SHIFT;
    const int tid = threadIdx.x;
    #pragma unroll
    for (int k = 0; k < 2; ++k) {
        int n = node0 + tid + k * 256;
        lcur[tid + k * 256] = (n < N_NODES) ? row_ptr[n] : 0;
    }
    __syncthreads();
    const int beg = b * SEGCAP;
    const int end = beg + gcur[b];
    for (int t = beg + tid; t < end; t += 256) {
        int2 p = pairs[t];
        int r = atomicAdd(&lcur[p.y - node0], 1);
        col[r] = p.x;
    }
    __syncthreads();
    #pragma unroll
    for (int k = 0; k < 2; ++k) {
        int n = tid + k * 256;
        int node = node0 + n;
        if (node < N_NODES) {
            int e = lcur[n];
            int pe = row_ptr[node + 1];
            for (int p = e; p < pe; ++p) col[p] = ZROW;
        }
    }
}

// ================= merged prep: prepack (64 blk) + padzero (2 blk) + cvt (12500 blk) =====
// prepack: Wp layout per layer [WrelP][WrootP], frag f=ks*8+n: lane l elem j =
// B[k=ks*32+(l>>4)*8+j][c=n*16+(l&15)]; residual fold +I on Wroot layers 1,2 (f32 add).

__global__ void prep_kernel(const float* __restrict__ in_feat, ushort* __restrict__ x0,
                            const float* __restrict__ Wrel, const float* __restrict__ Wroot,
                            ushort* __restrict__ Wp,
                            uint4* __restrict__ x0p, uint4* __restrict__ hAp,
                            uint4* __restrict__ hBp) {
    const int bid = blockIdx.x;
    const int tid = threadIdx.x;
    if (bid < 64) {
        // weight prepack
        int t = bid * 256 + tid;
        int layer = t >> 12;
        int m = (t >> 11) & 1;
        int frag = (t >> 6) & 31;
        int lane = t & 63;
        int ks = frag >> 3, n = frag & 7;
        int c = n * 16 + (lane & 15);
        int k0 = ks * 32 + (lane >> 4) * 8;
        ushort tmp[8];
        #pragma unroll
        for (int j = 0; j < 8; ++j) {
            int k = k0 + j;
            float w;
            if (m == 0) {
                w = Wrel[layer * 16384 + k * 128 + c];
            } else {
                w = Wroot[layer * 16384 + k * 128 + c];
                if ((layer == 1 || layer == 2) && k == c) w += 1.0f;
            }
            tmp[j] = f2bf(w);
        }
        *(uint4*)&Wp[(size_t)t * 8] = *(const uint4*)tmp;
    } else if (bid < 66) {
        // zero pad rows of x0/hA/hB
        const int npad4 = (N_PAD - N_NODES) * DIM / 8;
        int i = (bid - 64) * 256 + tid;
        uint4 z = make_uint4(0, 0, 0, 0);
        if (i < npad4) { x0p[i] = z; hAp[i] = z; hBp[i] = z; }
    } else {
        // f32 -> bf16 conversion of in_feat
        int i = ((bid - 66) * 256 + tid) * 4;
        float4 v = *(const float4*)&in_feat[i];
        uint2 r;
        r.x = (uint)f2bf(v.x) | ((uint)f2bf(v.y) << 16);
        r.y = (uint)f2bf(v.z) | ((uint)f2bf(v.w) << 16);
        *(uint2*)&x0[i] = r;
    }
}

// ================= fused gather + 2-pass MFMA + epilogue (128 threads, 16 rows) =================
// v10: same per-wave work as v7, half the block. Per block (2 waves, 16 rows, 4.3KB LDS):
//  Phase B: wave wv gathers rows wv*8..+7 as 4 PAIRS (8 gathers in flight) -> agg LDS.
//  Phase C: wave wv computes ALL 16 rows x cols wv*64..+63:
//           pass1 acc = agg(LDS) @ WrelP; pass2 acc += h(GLOBAL) @ WrootP(+I folded).
//  Epilogue: +bias, relu, LN (cross-col-half via lnbuf), direct scattered stores.
// grid 6252 (24.4 blocks/CU available) -> higher residency, finer tail than v7.
// MODE 0: relu+LN -> bf16 ; MODE 2: plain -> f32

template <int MODE>
__global__ __launch_bounds__(128, 8) void fused_kernel(const ushort* __restrict__ hb,
                                                       const int* __restrict__ row_ptr,
                                                       const int* __restrict__ col,
                                                       const ushort* __restrict__ Wp,
                                                       const float* __restrict__ brel,
                                                       const float* __restrict__ gamma,
                                                       const float* __restrict__ beta,
                                                       ushort* __restrict__ outb,
                                                       float* __restrict__ outf) {
    __shared__ char sA[16 * 256];        // agg bf16, XOR-swizzled (4 KB)
    __shared__ float2 lnbuf[16][2];      // per-row (s,q) partials per col-half
    const int tid = threadIdx.x;
    const int row0 = blockIdx.x * 16;
    const int lane = tid & 63;
    const int wv = tid >> 6;             // 0..1
    const int rsel = lane >> 4;
    const int c16 = lane & 15;

    // Phase B: wave wv gathers rows wv*8..+7, 2 rows per step, 8 h-gathers in flight
    const uint4* h4 = (const uint4*)hb;
    #pragma unroll 1
    for (int t = 0; t < 4; ++t) {
        const int rA = wv * 8 + 2 * t;
        const int rB = rA + 1;
        const int p0 = row_ptr[row0 + rA];
        const int p1 = row_ptr[row0 + rA + 1];
        const int p2 = row_ptr[row0 + rA + 2];
        const int itA = (p1 - p0) >> 4;
        const int itB = (p2 - p1) >> 4;
        int jA = p0 + rsel;
        int jB = p1 + rsel;
        const int iters = max(itA, itB);

        f32x2 a[4], b[4];
        #pragma unroll
        for (int u = 0; u < 4; ++u) { a[u] = (f32x2){0.f, 0.f}; b[u] = (f32x2){0.f, 0.f}; }

        for (int it = 0; it < iters; ++it) {
            int sA0 = ZROW, sA1 = ZROW, sA2 = ZROW, sA3 = ZROW;
            int sB0 = ZROW, sB1 = ZROW, sB2 = ZROW, sB3 = ZROW;
            if (it < itA) {
                sA0 = col[jA]; sA1 = col[jA + 4]; sA2 = col[jA + 8]; sA3 = col[jA + 12];
                jA += 16;
            }
            if (it < itB) {
                sB0 = col[jB]; sB1 = col[jB + 4]; sB2 = col[jB + 8]; sB3 = col[jB + 12];
                jB += 16;
            }
            uint4 pA0 = h4[(size_t)sA0 * 16 + c16];
            uint4 pA1 = h4[(size_t)sA1 * 16 + c16];
            uint4 pA2 = h4[(size_t)sA2 * 16 + c16];
            uint4 pA3 = h4[(size_t)sA3 * 16 + c16];
            uint4 pB0 = h4[(size_t)sB0 * 16 + c16];
            uint4 pB1 = h4[(size_t)sB1 * 16 + c16];
            uint4 pB2 = h4[(size_t)sB2 * 16 + c16];
            uint4 pB3 = h4[(size_t)sB3 * 16 + c16];
            accq(a, pA0); accq(a, pA1); accq(a, pA2); accq(a, pA3);
            accq(b, pB0); accq(b, pB1); accq(b, pB2); accq(b, pB3);
        }

        #pragma unroll
        for (int u = 0; u < 4; ++u) {
            float ax = a[u].x, ay = a[u].y, bx = b[u].x, by = b[u].y;
            ax += __shfl_xor(ax, 16); ay += __shfl_xor(ay, 16);
            bx += __shfl_xor(bx, 16); by += __shfl_xor(by, 16);
            ax += __shfl_xor(ax, 32); ay += __shfl_xor(ay, 32);
            bx += __shfl_xor(bx, 32); by += __shfl_xor(by, 32);
            a[u].x = ax; a[u].y = ay; b[u].x = bx; b[u].y = by;
        }
        if (rsel == 0) {
            uint4 o;
            o.x = (uint)f2bf(a[0].x) | ((uint)f2bf(a[0].y) << 16);
            o.y = (uint)f2bf(a[1].x) | ((uint)f2bf(a[1].y) << 16);
            o.z = (uint)f2bf(a[2].x) | ((uint)f2bf(a[2].y) << 16);
            o.w = (uint)f2bf(a[3].x) | ((uint)f2bf(a[3].y) << 16);
            *(uint4*)&sA[rA * 256 + ((c16 * 16) ^ ((rA & 7) << 4))] = o;
        } else if (rsel == 1) {
            uint4 o;
            o.x = (uint)f2bf(b[0].x) | ((uint)f2bf(b[0].y) << 16);
            o.y = (uint)f2bf(b[1].x) | ((uint)f2bf(b[1].y) << 16);
            o.z = (uint)f2bf(b[2].x) | ((uint)f2bf(b[2].y) << 16);
            o.w = (uint)f2bf(b[3].x) | ((uint)f2bf(b[3].y) << 16);
            *(uint4*)&sA[rB * 256 + ((c16 * 16) ^ ((rB & 7) << 4))] = o;
        }
    }
    __syncthreads();

    // Phase C: pass1 (agg from LDS) + pass2 (h from global); 16 rows x 64 cols per wave
    const int kg = lane >> 4;
    const int cl = lane & 15;
    const int ch = wv;                   // col half
    const size_t growa = (size_t)row0 + cl;
    const int abase = cl * 256 + kg * 16;
    const int aswz = (cl & 7) << 4;

    f32x4 acc[4];
    #pragma unroll
    for (int n = 0; n < 4; ++n) acc[n] = (f32x4){0.f, 0.f, 0.f, 0.f};

    const uint4* bR = (const uint4*)Wp + lane;             // rel frags
    const uint4* bT = (const uint4*)(Wp + 16384) + lane;   // root(+I) frags
    #pragma unroll
    for (int ks = 0; ks < 4; ++ks) {
        bf16x8 a = *(const bf16x8*)&sA[(abase + ks * 64) ^ aswz];
        #pragma unroll
        for (int n = 0; n < 4; ++n) {
            bf16x8 b = *(const bf16x8*)&bR[(ks * 8 + ch * 4 + n) * 64];
            acc[n] = __builtin_amdgcn_mfma_f32_16x16x32_bf16(a, b, acc[n], 0, 0, 0);
        }
    }
    #pragma unroll
    for (int ks = 0; ks < 4; ++ks) {
        bf16x8 a = *(const bf16x8*)&hb[growa * 128 + ks * 32 + kg * 8];
        #pragma unroll
        for (int n = 0; n < 4; ++n) {
            bf16x8 b = *(const bf16x8*)&bT[(ks * 8 + ch * 4 + n) * 64];
            acc[n] = __builtin_amdgcn_mfma_f32_16x16x32_bf16(a, b, acc[n], 0, 0, 0);
        }
    }

    float bias[4], gg[4], bb[4];
    #pragma unroll
    for (int n = 0; n < 4; ++n) {
        int cn = ch * 64 + n * 16 + cl;
        bias[n] = brel[cn];
        if (MODE != 2) { gg[n] = gamma[cn]; bb[n] = beta[cn]; }
    }

    if (MODE != 2) {
        float vv[4][4];   // [reg][n]
        #pragma unroll
        for (int reg = 0; reg < 4; ++reg) {
            float s = 0.f, q = 0.f;
            #pragma unroll
            for (int n = 0; n < 4; ++n) {
                float x = acc[n][reg] + bias[n];
                x = fmaxf(x, 0.f);
                vv[reg][n] = x; s += x; q += x * x;
            }
            #pragma unroll
            for (int m = 8; m >= 1; m >>= 1) { s += __shfl_xor(s, m); q += __shfl_xor(q, m); }
            if (cl == 0) lnbuf[kg * 4 + reg][ch] = make_float2(s, q);
        }
        __syncthreads();
        #pragma unroll
        for (int reg = 0; reg < 4; ++reg) {
            const int r = kg * 4 + reg;
            const size_t grow = (size_t)row0 + r;
            float2 e0 = lnbuf[r][0], e1 = lnbuf[r][1];
            float s = e0.x + e1.x;
            float q = e0.y + e1.y;
            float mu = s * (1.f / DIM);
            float var = q * (1.f / DIM) - mu * mu;
            float rinv = rsqrtf(var + LN_EPS);
            if (grow < N_NODES) {
                #pragma unroll
                for (int n = 0; n < 4; ++n) {
                    float y = (vv[reg][n] - mu) * rinv * gg[n] + bb[n];
                    outb[grow * DIM + ch * 64 + n * 16 + cl] = f2bf(y);
                }
            }
        }
    } else {
        #pragma unroll
        for (int reg = 0; reg < 4; ++reg) {
            const int r = kg * 4 + reg;
            const size_t grow = (size_t)row0 + r;
            if (grow < N_NODES) {
                #pragma unroll
                for (int n = 0; n < 4; ++n)
                    outf[grow * DIM + ch * 64 + n * 16 + cl] = acc[n][reg] + bias[n];
            }
        }
    }
}

// ================= launch =================

static inline size_t align256(size_t x) { return (x + 255) & ~(size_t)255; }

extern "C" void kernel_launch(void* const* d_in, const int* in_sizes, int n_in,
                              void* d_out, int out_size, void* d_ws, size_t ws_size,
                              hipStream_t stream) {
    const float* in_feat = (const float*)d_in[0];
    const int*   ei      = (const int*)d_in[1];
    const float* Wrel    = (const float*)d_in[2];
    const float* brel    = (const float*)d_in[3];
    const float* Wroot   = (const float*)d_in[4];
    const float* gamma   = (const float*)d_in[5];
    const float* beta    = (const float*)d_in[6];
    float* out = (float*)d_out;

    char* ws = (char*)d_ws;
    size_t off = 0;
    int* col = (int*)(ws + off);        off = align256(off + (size_t)COL_CAP * 4);
    int2* pairs = (int2*)(ws + off);    off = align256(off + (size_t)N_BKT * SEGCAP * 8);
    int* row_ptr = (int*)(ws + off);    off = align256(off + (size_t)(N_PAD + 2) * 4);
    int* gcur = (int*)(ws + off);       off = align256(off + (size_t)N_BKT * 4);
    int* bpad = (int*)(ws + off);       off = align256(off + (size_t)N_BKT * 4);
    int* bpadstart = (int*)(ws + off);  off = align256(off + (size_t)(N_BKT + 1) * 4);
    ushort* x0 = (ushort*)(ws + off);   off = align256(off + (size_t)N_PAD * DIM * 2);
    ushort* hA = (ushort*)(ws + off);   off = align256(off + (size_t)N_PAD * DIM * 2);
    ushort* hB = (ushort*)(ws + off);   off = align256(off + (size_t)N_PAD * DIM * 2);
    ushort* Wp = (ushort*)(ws + off);   off = align256(off + (size_t)4 * 2 * 128 * 128 * 2);
    (void)ws_size; (void)in_sizes; (void)n_in; (void)out_size;

    const int* src = ei;
    const int* dst = ei + N_EDGES;

    // CSR build: segmented scatter -> per-bucket degree/scan -> fill (padded x16)
    hipMemsetAsync(gcur, 0, (size_t)N_BKT * 4, stream);
    bscatter_kernel<<<NBLK, 256, 0, stream>>>(src, dst, gcur, pairs);
    ndeg_kernel<<<N_BKT, 256, 0, stream>>>(pairs, gcur, row_ptr, bpad);
    pscan_kernel<<<1, 256, 0, stream>>>(bpad, bpadstart);
    addbase_kernel<<<(N_PAD + 1 + 255) / 256, 256, 0, stream>>>(row_ptr, bpadstart);
    bfill_kernel<<<N_BKT, 256, 0, stream>>>(pairs, gcur, row_ptr, col);

    // merged prep: prepack + padzero + cvt (one launch)
    prep_kernel<<<66 + (N_NODES * DIM) / (4 * 256), 256, 0, stream>>>(
        in_feat, x0, Wrel, Wroot, Wp,
        (uint4*)(x0 + (size_t)N_NODES * DIM),
        (uint4*)(hA + (size_t)N_NODES * DIM),
        (uint4*)(hB + (size_t)N_NODES * DIM));

    const int grid = N_PAD / 16;   // 6252

    // layer 0 (no residual)
    fused_kernel<0><<<grid, 128, 0, stream>>>(x0, row_ptr, col, Wp, brel, gamma, beta, hA, nullptr);
    // layer 1 (residual folded into WrootP)
    fused_kernel<0><<<grid, 128, 0, stream>>>(hA, row_ptr, col, Wp + 32768, brel + DIM, gamma, beta, hB, nullptr);
    // layer 2 (residual folded into WrootP)
    fused_kernel<0><<<grid, 128, 0, stream>>>(hB, row_ptr, col, Wp + 2 * 32768, brel + 2 * DIM, gamma, beta, hA, nullptr);
    // layer 3 (plain conv, f32 output)
    fused_kernel<2><<<grid, 128, 0, stream>>>(hA, row_ptr, col, Wp + 3 * 32768, brel + 3 * DIM, gamma, beta, nullptr, out);
}

// Round 17
// 375.245 us; speedup vs baseline: 1.1477x; 1.1477x over previous
//
#include <hip/hip_runtime.h>
#include <cstddef>

#define N_NODES 100000
#define N_PAD   100032          // padded to 64-row multiple
#define N_EDGES 1600000
#define DIM 128
#define LN_EPS 1e-5f
#define ZROW   N_NODES          // dedicated all-zero feature row
#define COL_CAP 3200000         // >= E + 15*N (padded adjacency cap)

#define B_SHIFT 9
#define B_SIZE  512
#define N_BKT   196             // ceil(100032/512)
#define SEGCAP  10240           // per-bucket pair segment (mean 8163, ~23 sigma headroom)
#define EPB     4096            // edges per block in scatter pass
#define NBLK    ((N_EDGES + EPB - 1) / EPB)   // 391

typedef short bf16x8 __attribute__((ext_vector_type(8)));
typedef float f32x4 __attribute__((ext_vector_type(4)));
typedef float f32x2 __attribute__((ext_vector_type(2)));

__device__ __forceinline__ float asf(uint u) {
    union { uint i; float f; } c; c.i = u; return c.f;
}
__device__ __forceinline__ float bf2f(uint u) { return asf(u << 16); }
__device__ __forceinline__ ushort f2bf(float x) {
    union { float f; uint i; } c; c.f = x;
    uint r = c.i + 0x7fffu + ((c.i >> 16) & 1u);   // RNE
    return (ushort)(r >> 16);
}

// unpack one dword (2 bf16) and accumulate into a float2 (v_pk_add_f32)
__device__ __forceinline__ void accp(f32x2* acc, uint p) {
    f32x2 v;
    v.x = asf(p << 16);
    v.y = asf(p & 0xffff0000u);
    *acc += v;
}
__device__ __forceinline__ void accq(f32x2* a, uint4 p) {
    accp(&a[0], p.x); accp(&a[1], p.y); accp(&a[2], p.z); accp(&a[3], p.w);
}

// ================= CSR build: segmented scatter (no pre-histogram) =================

__global__ __launch_bounds__(256) void bscatter_kernel(const int* __restrict__ src,
                                                       const int* __restrict__ dst,
                                                       int* __restrict__ gcur,
                                                       int2* __restrict__ pairs) {
    __shared__ int lcnt[N_BKT];
    __shared__ int lbase[N_BKT];
    const int tid = threadIdx.x;
    if (tid < N_BKT) lcnt[tid] = 0;
    __syncthreads();
    const int base = blockIdx.x * EPB;
    int ls[16], ld[16];
    #pragma unroll
    for (int k = 0; k < 16; ++k) {
        int t = base + tid + k * 256;
        if (t < N_EDGES) {
            ls[k] = src[t]; ld[k] = dst[t];
            atomicAdd(&lcnt[ld[k] >> B_SHIFT], 1);
        } else ld[k] = -1;
    }
    __syncthreads();
    if (tid < N_BKT) lbase[tid] = lcnt[tid] ? atomicAdd(&gcur[tid], lcnt[tid]) : 0;
    __syncthreads();
    if (tid < N_BKT) lcnt[tid] = 0;
    __syncthreads();
    #pragma unroll
    for (int k = 0; k < 16; ++k) {
        if (ld[k] >= 0) {
            int b = ld[k] >> B_SHIFT;
            int r = atomicAdd(&lcnt[b], 1);
            pairs[b * SEGCAP + lbase[b] + r] = make_int2(ls[k], ld[k]);
        }
    }
}

// per-bucket degree count -> PADDED (mult of 16) exclusive scan, bucket-local.
__global__ __launch_bounds__(256) void ndeg_kernel(const int2* __restrict__ pairs,
                                                   const int* __restrict__ gcur,
                                                   int* __restrict__ row_ptr,
                                                   int* __restrict__ bpad) {
    __shared__ int ldeg[B_SIZE];
    __shared__ int ws4[4];
    const int b = blockIdx.x;
    const int node0 = b << B_SHIFT;
    const int tid = threadIdx.x;
    ldeg[tid] = 0; ldeg[tid + 256] = 0;
    __syncthreads();
    const int beg = b * SEGCAP;
    const int end = beg + gcur[b];
    for (int t = beg + tid; t < end; t += 256)
        atomicAdd(&ldeg[pairs[t].y - node0], 1);
    __syncthreads();
    const int d0 = (ldeg[2 * tid] + 15) & ~15;        // padded degrees
    const int d1 = (ldeg[2 * tid + 1] + 15) & ~15;
    const int sum2 = d0 + d1;
    const int lane = tid & 63, wv = tid >> 6;
    int incl = sum2;
    #pragma unroll
    for (int off = 1; off < 64; off <<= 1) {
        int t = __shfl_up(incl, off);
        if (lane >= off) incl += t;
    }
    if (lane == 63) ws4[wv] = incl;
    __syncthreads();
    int woff = 0;
    if (wv > 0) woff += ws4[0];
    if (wv > 1) woff += ws4[1];
    if (wv > 2) woff += ws4[2];
    const int e0 = woff + incl - sum2;                // bucket-local padded start
    const int n0 = node0 + 2 * tid;
    if (n0 < N_NODES)     row_ptr[n0]     = e0;
    if (n0 + 1 < N_NODES) row_ptr[n0 + 1] = e0 + d0;
    if (tid == 255) bpad[b] = woff + incl;            // bucket total
}

// scan of 196 bucket padded totals
__global__ __launch_bounds__(256) void pscan_kernel(const int* __restrict__ bpad,
                                                    int* __restrict__ bpadstart) {
    __shared__ int s[256];
    const int tid = threadIdx.x;
    int v = (tid < N_BKT) ? bpad[tid] : 0;
    s[tid] = v;
    __syncthreads();
    for (int off = 1; off < 256; off <<= 1) {
        int t = (tid >= off) ? s[tid - off] : 0;
        __syncthreads();
        s[tid] += t;
        __syncthreads();
    }
    if (tid < N_BKT) bpadstart[tid] = s[tid] - v;
    if (tid == N_BKT - 1) bpadstart[N_BKT] = s[tid];
}

// make row_ptr absolute; pad rows [N_NODES..N_PAD] get degree 0
__global__ void addbase_kernel(int* __restrict__ row_ptr, const int* __restrict__ bpadstart) {
    int n = blockIdx.x * 256 + threadIdx.x;
    if (n < N_NODES) row_ptr[n] += bpadstart[n >> B_SHIFT];
    else if (n <= N_PAD) row_ptr[n] = bpadstart[N_BKT];
}

// fill CSR + pad each node's slot tail with ZROW
__global__ __launch_bounds__(256) void bfill_kernel(const int2* __restrict__ pairs,
                                                    const int* __restrict__ gcur,
                                                    const int* __restrict__ row_ptr,
                                                    int* __restrict__ col) {
    __shared__ int lcur[B_SIZE];
    const int b = blockIdx.x;
    const int node0 = b << B_SHIFT;
    const int tid = threadIdx.x;
    #pragma unroll
    for (int k = 0; k < 2; ++k) {
        int n = node0 + tid + k * 256;
        lcur[tid + k * 256] = (n < N_NODES) ? row_ptr[n] : 0;
    }
    __syncthreads();
    const int beg = b * SEGCAP;
    const int end = beg + gcur[b];
    for (int t = beg + tid; t < end; t += 256) {
        int2 p = pairs[t];
        int r = atomicAdd(&lcur[p.y - node0], 1);
        col[r] = p.x;
    }
    __syncthreads();
    #pragma unroll
    for (int k = 0; k < 2; ++k) {
        int n = tid + k * 256;
        int node = node0 + n;
        if (node < N_NODES) {
            int e = lcur[n];
            int pe = row_ptr[node + 1];
            for (int p = e; p < pe; ++p) col[p] = ZROW;
        }
    }
}

// ================= merged prep: prepack (64 blk) + padzero (2 blk) + cvt (12500 blk) =====
// prepack: Wp layout per layer [WrelP][WrootP], frag f=ks*8+n: lane l elem j =
// B[k=ks*32+(l>>4)*8+j][c=n*16+(l&15)]; residual fold +I on Wroot layers 1,2 (f32 add).

__global__ void prep_kernel(const float* __restrict__ in_feat, ushort* __restrict__ x0,
                            const float* __restrict__ Wrel, const float* __restrict__ Wroot,
                            ushort* __restrict__ Wp,
                            uint4* __restrict__ x0p, uint4* __restrict__ hAp,
                            uint4* __restrict__ hBp) {
    const int bid = blockIdx.x;
    const int tid = threadIdx.x;
    if (bid < 64) {
        // weight prepack
        int t = bid * 256 + tid;
        int layer = t >> 12;
        int m = (t >> 11) & 1;
        int frag = (t >> 6) & 31;
        int lane = t & 63;
        int ks = frag >> 3, n = frag & 7;
        int c = n * 16 + (lane & 15);
        int k0 = ks * 32 + (lane >> 4) * 8;
        ushort tmp[8];
        #pragma unroll
        for (int j = 0; j < 8; ++j) {
            int k = k0 + j;
            float w;
            if (m == 0) {
                w = Wrel[layer * 16384 + k * 128 + c];
            } else {
                w = Wroot[layer * 16384 + k * 128 + c];
                if ((layer == 1 || layer == 2) && k == c) w += 1.0f;
            }
            tmp[j] = f2bf(w);
        }
        *(uint4*)&Wp[(size_t)t * 8] = *(const uint4*)tmp;
    } else if (bid < 66) {
        // zero pad rows of x0/hA/hB
        const int npad4 = (N_PAD - N_NODES) * DIM / 8;
        int i = (bid - 64) * 256 + tid;
        uint4 z = make_uint4(0, 0, 0, 0);
        if (i < npad4) { x0p[i] = z; hAp[i] = z; hBp[i] = z; }
    } else {
        // f32 -> bf16 conversion of in_feat
        int i = ((bid - 66) * 256 + tid) * 4;
        float4 v = *(const float4*)&in_feat[i];
        uint2 r;
        r.x = (uint)f2bf(v.x) | ((uint)f2bf(v.y) << 16);
        r.y = (uint)f2bf(v.z) | ((uint)f2bf(v.w) << 16);
        *(uint2*)&x0[i] = r;
    }
}

// ================= fused gather + 2-pass MFMA + epilogue (256 threads, 32 rows) =================
// Round-15 config (session best: 381.5 us). Per block (4 waves, 32 rows, 8.7KB LDS, VGPR 40):
//  Phase B: wave wv gathers rows wv*8..+7 as 4 PAIRS (8 gathers in flight) -> agg LDS.
//  Phase C: wave (rh=wv&1, ch=wv>>1) computes rows rh*16..+15 x cols ch*64..+63:
//           pass1 acc = agg(LDS) @ WrelP; pass2 acc += h(GLOBAL) @ WrootP(+I folded).
//  Epilogue: +bias, relu, LN (cross-col-half via lnbuf), direct scattered stores.
// MODE 0: relu+LN -> bf16 ; MODE 2: plain -> f32

template <int MODE>
__global__ __launch_bounds__(256, 6) void fused_kernel(const ushort* __restrict__ hb,
                                                       const int* __restrict__ row_ptr,
                                                       const int* __restrict__ col,
                                                       const ushort* __restrict__ Wp,
                                                       const float* __restrict__ brel,
                                                       const float* __restrict__ gamma,
                                                       const float* __restrict__ beta,
                                                       ushort* __restrict__ outb,
                                                       float* __restrict__ outf) {
    __shared__ char sA[32 * 256];        // agg bf16, XOR-swizzled (8 KB)
    __shared__ float2 lnbuf[32][2];      // per-row (s,q) partials per col-half
    const int tid = threadIdx.x;
    const int row0 = blockIdx.x * 32;
    const int lane = tid & 63;
    const int wv = tid >> 6;             // 0..3
    const int rsel = lane >> 4;
    const int c16 = lane & 15;

    // Phase B: gather rows wv*8..+7, 2 rows per step, 8 h-gathers in flight
    const uint4* h4 = (const uint4*)hb;
    #pragma unroll 1
    for (int t = 0; t < 4; ++t) {
        const int rA = wv * 8 + 2 * t;
        const int rB = rA + 1;
        const int p0 = row_ptr[row0 + rA];
        const int p1 = row_ptr[row0 + rA + 1];
        const int p2 = row_ptr[row0 + rA + 2];
        const int itA = (p1 - p0) >> 4;
        const int itB = (p2 - p1) >> 4;
        int jA = p0 + rsel;
        int jB = p1 + rsel;
        const int iters = max(itA, itB);

        f32x2 a[4], b[4];
        #pragma unroll
        for (int u = 0; u < 4; ++u) { a[u] = (f32x2){0.f, 0.f}; b[u] = (f32x2){0.f, 0.f}; }

        for (int it = 0; it < iters; ++it) {
            int sA0 = ZROW, sA1 = ZROW, sA2 = ZROW, sA3 = ZROW;
            int sB0 = ZROW, sB1 = ZROW, sB2 = ZROW, sB3 = ZROW;
            if (it < itA) {
                sA0 = col[jA]; sA1 = col[jA + 4]; sA2 = col[jA + 8]; sA3 = col[jA + 12];
                jA += 16;
            }
            if (it < itB) {
                sB0 = col[jB]; sB1 = col[jB + 4]; sB2 = col[jB + 8]; sB3 = col[jB + 12];
                jB += 16;
            }
            uint4 pA0 = h4[(size_t)sA0 * 16 + c16];
            uint4 pA1 = h4[(size_t)sA1 * 16 + c16];
            uint4 pA2 = h4[(size_t)sA2 * 16 + c16];
            uint4 pA3 = h4[(size_t)sA3 * 16 + c16];
            uint4 pB0 = h4[(size_t)sB0 * 16 + c16];
            uint4 pB1 = h4[(size_t)sB1 * 16 + c16];
            uint4 pB2 = h4[(size_t)sB2 * 16 + c16];
            uint4 pB3 = h4[(size_t)sB3 * 16 + c16];
            accq(a, pA0); accq(a, pA1); accq(a, pA2); accq(a, pA3);
            accq(b, pB0); accq(b, pB1); accq(b, pB2); accq(b, pB3);
        }

        #pragma unroll
        for (int u = 0; u < 4; ++u) {
            float ax = a[u].x, ay = a[u].y, bx = b[u].x, by = b[u].y;
            ax += __shfl_xor(ax, 16); ay += __shfl_xor(ay, 16);
            bx += __shfl_xor(bx, 16); by += __shfl_xor(by, 16);
            ax += __shfl_xor(ax, 32); ay += __shfl_xor(ay, 32);
            bx += __shfl_xor(bx, 32); by += __shfl_xor(by, 32);
            a[u].x = ax; a[u].y = ay; b[u].x = bx; b[u].y = by;
        }
        if (rsel == 0) {
            uint4 o;
            o.x = (uint)f2bf(a[0].x) | ((uint)f2bf(a[0].y) << 16);
            o.y = (uint)f2bf(a[1].x) | ((uint)f2bf(a[1].y) << 16);
            o.z = (uint)f2bf(a[2].x) | ((uint)f2bf(a[2].y) << 16);
            o.w = (uint)f2bf(a[3].x) | ((uint)f2bf(a[3].y) << 16);
            *(uint4*)&sA[rA * 256 + ((c16 * 16) ^ ((rA & 7) << 4))] = o;
        } else if (rsel == 1) {
            uint4 o;
            o.x = (uint)f2bf(b[0].x) | ((uint)f2bf(b[0].y) << 16);
            o.y = (uint)f2bf(b[1].x) | ((uint)f2bf(b[1].y) << 16);
            o.z = (uint)f2bf(b[2].x) | ((uint)f2bf(b[2].y) << 16);
            o.w = (uint)f2bf(b[3].x) | ((uint)f2bf(b[3].y) << 16);
            *(uint4*)&sA[rB * 256 + ((c16 * 16) ^ ((rB & 7) << 4))] = o;
        }
    }
    __syncthreads();

    // Phase C: pass1 (agg from LDS) + pass2 (h from global), 16 rows x 64 cols per wave
    const int kg = lane >> 4;
    const int cl = lane & 15;
    const int rh = wv & 1;               // row half
    const int ch = wv >> 1;              // col half
    const int ra = rh * 16 + cl;
    const size_t growa = (size_t)row0 + ra;
    const int abase = ra * 256 + kg * 16;
    const int aswz = (ra & 7) << 4;

    f32x4 acc[4];
    #pragma unroll
    for (int n = 0; n < 4; ++n) acc[n] = (f32x4){0.f, 0.f, 0.f, 0.f};

    const uint4* bR = (const uint4*)Wp + lane;             // rel frags
    const uint4* bT = (const uint4*)(Wp + 16384) + lane;   // root(+I) frags
    #pragma unroll
    for (int ks = 0; ks < 4; ++ks) {
        bf16x8 a = *(const bf16x8*)&sA[(abase + ks * 64) ^ aswz];
        #pragma unroll
        for (int n = 0; n < 4; ++n) {
            bf16x8 b = *(const bf16x8*)&bR[(ks * 8 + ch * 4 + n) * 64];
            acc[n] = __builtin_amdgcn_mfma_f32_16x16x32_bf16(a, b, acc[n], 0, 0, 0);
        }
    }
    #pragma unroll
    for (int ks = 0; ks < 4; ++ks) {
        bf16x8 a = *(const bf16x8*)&hb[growa * 128 + ks * 32 + kg * 8];
        #pragma unroll
        for (int n = 0; n < 4; ++n) {
            bf16x8 b = *(const bf16x8*)&bT[(ks * 8 + ch * 4 + n) * 64];
            acc[n] = __builtin_amdgcn_mfma_f32_16x16x32_bf16(a, b, acc[n], 0, 0, 0);
        }
    }

    float bias[4], gg[4], bb[4];
    #pragma unroll
    for (int n = 0; n < 4; ++n) {
        int cn = ch * 64 + n * 16 + cl;
        bias[n] = brel[cn];
        if (MODE != 2) { gg[n] = gamma[cn]; bb[n] = beta[cn]; }
    }

    if (MODE != 2) {
        float vv[4][4];   // [reg][n]
        #pragma unroll
        for (int reg = 0; reg < 4; ++reg) {
            float s = 0.f, q = 0.f;
            #pragma unroll
            for (int n = 0; n < 4; ++n) {
                float x = acc[n][reg] + bias[n];
                x = fmaxf(x, 0.f);
                vv[reg][n] = x; s += x; q += x * x;
            }
            #pragma unroll
            for (int m = 8; m >= 1; m >>= 1) { s += __shfl_xor(s, m); q += __shfl_xor(q, m); }
            if (cl == 0) lnbuf[rh * 16 + kg * 4 + reg][ch] = make_float2(s, q);
        }
        __syncthreads();
        #pragma unroll
        for (int reg = 0; reg < 4; ++reg) {
            const int r = rh * 16 + kg * 4 + reg;
            const size_t grow = (size_t)row0 + r;
            float2 e0 = lnbuf[r][0], e1 = lnbuf[r][1];
            float s = e0.x + e1.x;
            float q = e0.y + e1.y;
            float mu = s * (1.f / DIM);
            float var = q * (1.f / DIM) - mu * mu;
            float rinv = rsqrtf(var + LN_EPS);
            if (grow < N_NODES) {
                #pragma unroll
                for (int n = 0; n < 4; ++n) {
                    float y = (vv[reg][n] - mu) * rinv * gg[n] + bb[n];
                    outb[grow * DIM + ch * 64 + n * 16 + cl] = f2bf(y);
                }
            }
        }
    } else {
        #pragma unroll
        for (int reg = 0; reg < 4; ++reg) {
            const int r = rh * 16 + kg * 4 + reg;
            const size_t grow = (size_t)row0 + r;
            if (grow < N_NODES) {
                #pragma unroll
                for (int n = 0; n < 4; ++n)
                    outf[grow * DIM + ch * 64 + n * 16 + cl] = acc[n][reg] + bias[n];
            }
        }
    }
}

// ================= launch =================

static inline size_t align256(size_t x) { return (x + 255) & ~(size_t)255; }

extern "C" void kernel_launch(void* const* d_in, const int* in_sizes, int n_in,
                              void* d_out, int out_size, void* d_ws, size_t ws_size,
                              hipStream_t stream) {
    const float* in_feat = (const float*)d_in[0];
    const int*   ei      = (const int*)d_in[1];
    const float* Wrel    = (const float*)d_in[2];
    const float* brel    = (const float*)d_in[3];
    const float* Wroot   = (const float*)d_in[4];
    const float* gamma   = (const float*)d_in[5];
    const float* beta    = (const float*)d_in[6];
    float* out = (float*)d_out;

    char* ws = (char*)d_ws;
    size_t off = 0;
    int* col = (int*)(ws + off);        off = align256(off + (size_t)COL_CAP * 4);
    int2* pairs = (int2*)(ws + off);    off = align256(off + (size_t)N_BKT * SEGCAP * 8);
    int* row_ptr = (int*)(ws + off);    off = align256(off + (size_t)(N_PAD + 2) * 4);
    int* gcur = (int*)(ws + off);       off = align256(off + (size_t)N_BKT * 4);
    int* bpad = (int*)(ws + off);       off = align256(off + (size_t)N_BKT * 4);
    int* bpadstart = (int*)(ws + off);  off = align256(off + (size_t)(N_BKT + 1) * 4);
    ushort* x0 = (ushort*)(ws + off);   off = align256(off + (size_t)N_PAD * DIM * 2);
    ushort* hA = (ushort*)(ws + off);   off = align256(off + (size_t)N_PAD * DIM * 2);
    ushort* hB = (ushort*)(ws + off);   off = align256(off + (size_t)N_PAD * DIM * 2);
    ushort* Wp = (ushort*)(ws + off);   off = align256(off + (size_t)4 * 2 * 128 * 128 * 2);
    (void)ws_size; (void)in_sizes; (void)n_in; (void)out_size;

    const int* src = ei;
    const int* dst = ei + N_EDGES;

    // CSR build: segmented scatter -> per-bucket degree/scan -> fill (padded x16)
    hipMemsetAsync(gcur, 0, (size_t)N_BKT * 4, stream);
    bscatter_kernel<<<NBLK, 256, 0, stream>>>(src, dst, gcur, pairs);
    ndeg_kernel<<<N_BKT, 256, 0, stream>>>(pairs, gcur, row_ptr, bpad);
    pscan_kernel<<<1, 256, 0, stream>>>(bpad, bpadstart);
    addbase_kernel<<<(N_PAD + 1 + 255) / 256, 256, 0, stream>>>(row_ptr, bpadstart);
    bfill_kernel<<<N_BKT, 256, 0, stream>>>(pairs, gcur, row_ptr, col);

    // merged prep: prepack + padzero + cvt (one launch)
    prep_kernel<<<66 + (N_NODES * DIM) / (4 * 256), 256, 0, stream>>>(
        in_feat, x0, Wrel, Wroot, Wp,
        (uint4*)(x0 + (size_t)N_NODES * DIM),
        (uint4*)(hA + (size_t)N_NODES * DIM),
        (uint4*)(hB + (size_t)N_NODES * DIM));

    const int grid = N_PAD / 32;   // 3126

    // layer 0 (no residual)
    fused_kernel<0><<<grid, 256, 0, stream>>>(x0, row_ptr, col, Wp, brel, gamma, beta, hA, nullptr);
    // layer 1 (residual folded into WrootP)
    fused_kernel<0><<<grid, 256, 0, stream>>>(hA, row_ptr, col, Wp + 32768, brel + DIM, gamma, beta, hB, nullptr);
    // layer 2 (residual folded into WrootP)
    fused_kernel<0><<<grid, 256, 0, stream>>>(hB, row_ptr, col, Wp + 2 * 32768, brel + 2 * DIM, gamma, beta, hA, nullptr);
    // layer 3 (plain conv, f32 output)
    fused_kernel<2><<<grid, 256, 0, stream>>>(hA, row_ptr, col, Wp + 3 * 32768, brel + 3 * DIM, gamma, beta, nullptr, out);
}

// Round 18
// 363.966 us; speedup vs baseline: 1.1833x; 1.0310x over previous
//
#include <hip/hip_runtime.h>
#include <cstddef>

#define N_NODES 100000
#define N_PAD   100032          // padded to 64-row multiple
#define N_EDGES 1600000
#define DIM 128
#define LN_EPS 1e-5f
#define ZROW   N_NODES          // dedicated all-zero feature row
#define COL_CAP 3200000         // >= E + 15*N (padded adjacency cap)

#define B_SHIFT 9
#define B_SIZE  512
#define N_BKT   196             // ceil(100032/512)
#define SEGCAP  10240           // per-bucket pair segment (mean 8163, ~23 sigma headroom)
#define EPB     4096            // edges per block in scatter pass
#define NBLK    ((N_EDGES + EPB - 1) / EPB)   // 391

typedef short bf16x8 __attribute__((ext_vector_type(8)));
typedef float f32x4 __attribute__((ext_vector_type(4)));
typedef float f32x2 __attribute__((ext_vector_type(2)));

__device__ __forceinline__ float asf(uint u) {
    union { uint i; float f; } c; c.i = u; return c.f;
}
__device__ __forceinline__ float bf2f(uint u) { return asf(u << 16); }
__device__ __forceinline__ ushort f2bf(float x) {
    union { float f; uint i; } c; c.f = x;
    uint r = c.i + 0x7fffu + ((c.i >> 16) & 1u);   // RNE
    return (ushort)(r >> 16);
}

// unpack one dword (2 bf16) and accumulate into a float2 (v_pk_add_f32)
__device__ __forceinline__ void accp(f32x2* acc, uint p) {
    f32x2 v;
    v.x = asf(p << 16);
    v.y = asf(p & 0xffff0000u);
    *acc += v;
}
__device__ __forceinline__ void accq(f32x2* a, uint4 p) {
    accp(&a[0], p.x); accp(&a[1], p.y); accp(&a[2], p.z); accp(&a[3], p.w);
}

// ================= CSR build: segmented scatter (no pre-histogram) =================

__global__ __launch_bounds__(256) void bscatter_kernel(const int* __restrict__ src,
                                                       const int* __restrict__ dst,
                                                       int* __restrict__ gcur,
                                                       int2* __restrict__ pairs) {
    __shared__ int lcnt[N_BKT];
    __shared__ int lbase[N_BKT];
    const int tid = threadIdx.x;
    if (tid < N_BKT) lcnt[tid] = 0;
    __syncthreads();
    const int base = blockIdx.x * EPB;
    int ls[16], ld[16];
    #pragma unroll
    for (int k = 0; k < 16; ++k) {
        int t = base + tid + k * 256;
        if (t < N_EDGES) {
            ls[k] = src[t]; ld[k] = dst[t];
            atomicAdd(&lcnt[ld[k] >> B_SHIFT], 1);
        } else ld[k] = -1;
    }
    __syncthreads();
    if (tid < N_BKT) lbase[tid] = lcnt[tid] ? atomicAdd(&gcur[tid], lcnt[tid]) : 0;
    __syncthreads();
    if (tid < N_BKT) lcnt[tid] = 0;
    __syncthreads();
    #pragma unroll
    for (int k = 0; k < 16; ++k) {
        if (ld[k] >= 0) {
            int b = ld[k] >> B_SHIFT;
            int r = atomicAdd(&lcnt[b], 1);
            pairs[b * SEGCAP + lbase[b] + r] = make_int2(ls[k], ld[k]);
        }
    }
}

// per-bucket degree count -> PADDED (mult of 16) exclusive scan, bucket-local.
__global__ __launch_bounds__(256) void ndeg_kernel(const int2* __restrict__ pairs,
                                                   const int* __restrict__ gcur,
                                                   int* __restrict__ row_ptr,
                                                   int* __restrict__ bpad) {
    __shared__ int ldeg[B_SIZE];
    __shared__ int ws4[4];
    const int b = blockIdx.x;
    const int node0 = b << B_SHIFT;
    const int tid = threadIdx.x;
    ldeg[tid] = 0; ldeg[tid + 256] = 0;
    __syncthreads();
    const int beg = b * SEGCAP;
    const int end = beg + gcur[b];
    for (int t = beg + tid; t < end; t += 256)
        atomicAdd(&ldeg[pairs[t].y - node0], 1);
    __syncthreads();
    const int d0 = (ldeg[2 * tid] + 15) & ~15;        // padded degrees
    const int d1 = (ldeg[2 * tid + 1] + 15) & ~15;
    const int sum2 = d0 + d1;
    const int lane = tid & 63, wv = tid >> 6;
    int incl = sum2;
    #pragma unroll
    for (int off = 1; off < 64; off <<= 1) {
        int t = __shfl_up(incl, off);
        if (lane >= off) incl += t;
    }
    if (lane == 63) ws4[wv] = incl;
    __syncthreads();
    int woff = 0;
    if (wv > 0) woff += ws4[0];
    if (wv > 1) woff += ws4[1];
    if (wv > 2) woff += ws4[2];
    const int e0 = woff + incl - sum2;                // bucket-local padded start
    const int n0 = node0 + 2 * tid;
    if (n0 < N_NODES)     row_ptr[n0]     = e0;
    if (n0 + 1 < N_NODES) row_ptr[n0 + 1] = e0 + d0;
    if (tid == 255) bpad[b] = woff + incl;            // bucket total
}

// scan of 196 bucket padded totals
__global__ __launch_bounds__(256) void pscan_kernel(const int* __restrict__ bpad,
                                                    int* __restrict__ bpadstart) {
    __shared__ int s[256];
    const int tid = threadIdx.x;
    int v = (tid < N_BKT) ? bpad[tid] : 0;
    s[tid] = v;
    __syncthreads();
    for (int off = 1; off < 256; off <<= 1) {
        int t = (tid >= off) ? s[tid - off] : 0;
        __syncthreads();
        s[tid] += t;
        __syncthreads();
    }
    if (tid < N_BKT) bpadstart[tid] = s[tid] - v;
    if (tid == N_BKT - 1) bpadstart[N_BKT] = s[tid];
}

// make row_ptr absolute; pad rows [N_NODES..N_PAD] get degree 0
__global__ void addbase_kernel(int* __restrict__ row_ptr, const int* __restrict__ bpadstart) {
    int n = blockIdx.x * 256 + threadIdx.x;
    if (n < N_NODES) row_ptr[n] += bpadstart[n >> B_SHIFT];
    else if (n <= N_PAD) row_ptr[n] = bpadstart[N_BKT];
}

// fill CSR + pad each node's slot tail with ZROW
__global__ __launch_bounds__(256) void bfill_kernel(const int2* __restrict__ pairs,
                                                    const int* __restrict__ gcur,
                                                    const int* __restrict__ row_ptr,
                                                    int* __restrict__ col) {
    __shared__ int lcur[B_SIZE];
    const int b = blockIdx.x;
    const int node0 = b << B_SHIFT;
    const int tid = threadIdx.x;
    #pragma unroll
    for (int k = 0; k < 2; ++k) {
        int n = node0 + tid + k * 256;
        lcur[tid + k * 256] = (n < N_NODES) ? row_ptr[n] : 0;
    }
    __syncthreads();
    const int beg = b * SEGCAP;
    const int end = beg + gcur[b];
    for (int t = beg + tid; t < end; t += 256) {
        int2 p = pairs[t];
        int r = atomicAdd(&lcur[p.y - node0], 1);
        col[r] = p.x;
    }
    __syncthreads();
    #pragma unroll
    for (int k = 0; k < 2; ++k) {
        int n = tid + k * 256;
        int node = node0 + n;
        if (node < N_NODES) {
            int e = lcur[n];
            int pe = row_ptr[node + 1];
            for (int p = e; p < pe; ++p) col[p] = ZROW;
        }
    }
}

// ================= merged prep: prepack (64 blk) + padzero (2 blk) + cvt (12500 blk) =====
// prepack: Wp layout per layer [WrelP][WrootP], frag f=ks*8+n: lane l elem j =
// B[k=ks*32+(l>>4)*8+j][c=n*16+(l&15)]; residual fold +I on Wroot layers 1,2 (f32 add).

__global__ void prep_kernel(const float* __restrict__ in_feat, ushort* __restrict__ x0,
                            const float* __restrict__ Wrel, const float* __restrict__ Wroot,
                            ushort* __restrict__ Wp,
                            uint4* __restrict__ x0p, uint4* __restrict__ hAp,
                            uint4* __restrict__ hBp) {
    const int bid = blockIdx.x;
    const int tid = threadIdx.x;
    if (bid < 64) {
        // weight prepack
        int t = bid * 256 + tid;
        int layer = t >> 12;
        int m = (t >> 11) & 1;
        int frag = (t >> 6) & 31;
        int lane = t & 63;
        int ks = frag >> 3, n = frag & 7;
        int c = n * 16 + (lane & 15);
        int k0 = ks * 32 + (lane >> 4) * 8;
        ushort tmp[8];
        #pragma unroll
        for (int j = 0; j < 8; ++j) {
            int k = k0 + j;
            float w;
            if (m == 0) {
                w = Wrel[layer * 16384 + k * 128 + c];
            } else {
                w = Wroot[layer * 16384 + k * 128 + c];
                if ((layer == 1 || layer == 2) && k == c) w += 1.0f;
            }
            tmp[j] = f2bf(w);
        }
        *(uint4*)&Wp[(size_t)t * 8] = *(const uint4*)tmp;
    } else if (bid < 66) {
        // zero pad rows of x0/hA/hB
        const int npad4 = (N_PAD - N_NODES) * DIM / 8;
        int i = (bid - 64) * 256 + tid;
        uint4 z = make_uint4(0, 0, 0, 0);
        if (i < npad4) { x0p[i] = z; hAp[i] = z; hBp[i] = z; }
    } else {
        // f32 -> bf16 conversion of in_feat
        int i = ((bid - 66) * 256 + tid) * 4;
        float4 v = *(const float4*)&in_feat[i];
        uint2 r;
        r.x = (uint)f2bf(v.x) | ((uint)f2bf(v.y) << 16);
        r.y = (uint)f2bf(v.z) | ((uint)f2bf(v.w) << 16);
        *(uint2*)&x0[i] = r;
    }
}

// ================= fused gather + 2-pass MFMA + epilogue (256 threads, 32 rows) =================
// v11 = round-15 config + pass-2 MFMA hoisted BEFORE the barrier (pass-2 reads only the
// wave's own h rows from global + Wroot frags — no LDS dependency — so it overlaps with
// straggler waves' gathers and fills gather stall cycles).
// Per block (4 waves, 32 rows, 8.7KB LDS):
//  Phase B: wave wv gathers rows wv*8..+7 as 4 PAIRS (8 gathers in flight) -> agg LDS.
//  Phase B2 (pre-barrier): acc = h(GLOBAL) @ WrootP(+I folded); bias/gamma/beta loads.
//  Phase C (post-barrier): acc += agg(LDS) @ WrelP; +bias, relu, LN (lnbuf), stores.
// MODE 0: relu+LN -> bf16 ; MODE 2: plain -> f32

template <int MODE>
__global__ __launch_bounds__(256, 6) void fused_kernel(const ushort* __restrict__ hb,
                                                       const int* __restrict__ row_ptr,
                                                       const int* __restrict__ col,
                                                       const ushort* __restrict__ Wp,
                                                       const float* __restrict__ brel,
                                                       const float* __restrict__ gamma,
                                                       const float* __restrict__ beta,
                                                       ushort* __restrict__ outb,
                                                       float* __restrict__ outf) {
    __shared__ char sA[32 * 256];        // agg bf16, XOR-swizzled (8 KB)
    __shared__ float2 lnbuf[32][2];      // per-row (s,q) partials per col-half
    const int tid = threadIdx.x;
    const int row0 = blockIdx.x * 32;
    const int lane = tid & 63;
    const int wv = tid >> 6;             // 0..3
    const int rsel = lane >> 4;
    const int c16 = lane & 15;

    // Phase B: gather rows wv*8..+7, 2 rows per step, 8 h-gathers in flight
    const uint4* h4 = (const uint4*)hb;
    #pragma unroll 1
    for (int t = 0; t < 4; ++t) {
        const int rA = wv * 8 + 2 * t;
        const int rB = rA + 1;
        const int p0 = row_ptr[row0 + rA];
        const int p1 = row_ptr[row0 + rA + 1];
        const int p2 = row_ptr[row0 + rA + 2];
        const int itA = (p1 - p0) >> 4;
        const int itB = (p2 - p1) >> 4;
        int jA = p0 + rsel;
        int jB = p1 + rsel;
        const int iters = max(itA, itB);

        f32x2 a[4], b[4];
        #pragma unroll
        for (int u = 0; u < 4; ++u) { a[u] = (f32x2){0.f, 0.f}; b[u] = (f32x2){0.f, 0.f}; }

        for (int it = 0; it < iters; ++it) {
            int sA0 = ZROW, sA1 = ZROW, sA2 = ZROW, sA3 = ZROW;
            int sB0 = ZROW, sB1 = ZROW, sB2 = ZROW, sB3 = ZROW;
            if (it < itA) {
                sA0 = col[jA]; sA1 = col[jA + 4]; sA2 = col[jA + 8]; sA3 = col[jA + 12];
                jA += 16;
            }
            if (it < itB) {
                sB0 = col[jB]; sB1 = col[jB + 4]; sB2 = col[jB + 8]; sB3 = col[jB + 12];
                jB += 16;
            }
            uint4 pA0 = h4[(size_t)sA0 * 16 + c16];
            uint4 pA1 = h4[(size_t)sA1 * 16 + c16];
            uint4 pA2 = h4[(size_t)sA2 * 16 + c16];
            uint4 pA3 = h4[(size_t)sA3 * 16 + c16];
            uint4 pB0 = h4[(size_t)sB0 * 16 + c16];
            uint4 pB1 = h4[(size_t)sB1 * 16 + c16];
            uint4 pB2 = h4[(size_t)sB2 * 16 + c16];
            uint4 pB3 = h4[(size_t)sB3 * 16 + c16];
            accq(a, pA0); accq(a, pA1); accq(a, pA2); accq(a, pA3);
            accq(b, pB0); accq(b, pB1); accq(b, pB2); accq(b, pB3);
        }

        #pragma unroll
        for (int u = 0; u < 4; ++u) {
            float ax = a[u].x, ay = a[u].y, bx = b[u].x, by = b[u].y;
            ax += __shfl_xor(ax, 16); ay += __shfl_xor(ay, 16);
            bx += __shfl_xor(bx, 16); by += __shfl_xor(by, 16);
            ax += __shfl_xor(ax, 32); ay += __shfl_xor(ay, 32);
            bx += __shfl_xor(bx, 32); by += __shfl_xor(by, 32);
            a[u].x = ax; a[u].y = ay; b[u].x = bx; b[u].y = by;
        }
        if (rsel == 0) {
            uint4 o;
            o.x = (uint)f2bf(a[0].x) | ((uint)f2bf(a[0].y) << 16);
            o.y = (uint)f2bf(a[1].x) | ((uint)f2bf(a[1].y) << 16);
            o.z = (uint)f2bf(a[2].x) | ((uint)f2bf(a[2].y) << 16);
            o.w = (uint)f2bf(a[3].x) | ((uint)f2bf(a[3].y) << 16);
            *(uint4*)&sA[rA * 256 + ((c16 * 16) ^ ((rA & 7) << 4))] = o;
        } else if (rsel == 1) {
            uint4 o;
            o.x = (uint)f2bf(b[0].x) | ((uint)f2bf(b[0].y) << 16);
            o.y = (uint)f2bf(b[1].x) | ((uint)f2bf(b[1].y) << 16);
            o.z = (uint)f2bf(b[2].x) | ((uint)f2bf(b[2].y) << 16);
            o.w = (uint)f2bf(b[3].x) | ((uint)f2bf(b[3].y) << 16);
            *(uint4*)&sA[rB * 256 + ((c16 * 16) ^ ((rB & 7) << 4))] = o;
        }
    }

    // Phase B2 (PRE-barrier): pass-2 MFMA — no LDS dependency, overlaps straggler gathers
    const int kg = lane >> 4;
    const int cl = lane & 15;
    const int rh = wv & 1;               // row half
    const int ch = wv >> 1;              // col half
    const int ra = rh * 16 + cl;
    const size_t growa = (size_t)row0 + ra;

    f32x4 acc[4];
    #pragma unroll
    for (int n = 0; n < 4; ++n) acc[n] = (f32x4){0.f, 0.f, 0.f, 0.f};

    const uint4* bT = (const uint4*)(Wp + 16384) + lane;   // root(+I) frags
    #pragma unroll
    for (int ks = 0; ks < 4; ++ks) {
        bf16x8 a = *(const bf16x8*)&hb[growa * 128 + ks * 32 + kg * 8];
        #pragma unroll
        for (int n = 0; n < 4; ++n) {
            bf16x8 b = *(const bf16x8*)&bT[(ks * 8 + ch * 4 + n) * 64];
            acc[n] = __builtin_amdgcn_mfma_f32_16x16x32_bf16(a, b, acc[n], 0, 0, 0);
        }
    }

    float bias[4], gg[4], bb[4];
    #pragma unroll
    for (int n = 0; n < 4; ++n) {
        int cn = ch * 64 + n * 16 + cl;
        bias[n] = brel[cn];
        if (MODE != 2) { gg[n] = gamma[cn]; bb[n] = beta[cn]; }
    }

    __syncthreads();

    // Phase C: pass-1 (agg from LDS) + epilogue
    const int abase = ra * 256 + kg * 16;
    const int aswz = (ra & 7) << 4;
    const uint4* bR = (const uint4*)Wp + lane;             // rel frags
    #pragma unroll
    for (int ks = 0; ks < 4; ++ks) {
        bf16x8 a = *(const bf16x8*)&sA[(abase + ks * 64) ^ aswz];
        #pragma unroll
        for (int n = 0; n < 4; ++n) {
            bf16x8 b = *(const bf16x8*)&bR[(ks * 8 + ch * 4 + n) * 64];
            acc[n] = __builtin_amdgcn_mfma_f32_16x16x32_bf16(a, b, acc[n], 0, 0, 0);
        }
    }

    if (MODE != 2) {
        float vv[4][4];   // [reg][n]
        #pragma unroll
        for (int reg = 0; reg < 4; ++reg) {
            float s = 0.f, q = 0.f;
            #pragma unroll
            for (int n = 0; n < 4; ++n) {
                float x = acc[n][reg] + bias[n];
                x = fmaxf(x, 0.f);
                vv[reg][n] = x; s += x; q += x * x;
            }
            #pragma unroll
            for (int m = 8; m >= 1; m >>= 1) { s += __shfl_xor(s, m); q += __shfl_xor(q, m); }
            if (cl == 0) lnbuf[rh * 16 + kg * 4 + reg][ch] = make_float2(s, q);
        }
        __syncthreads();
        #pragma unroll
        for (int reg = 0; reg < 4; ++reg) {
            const int r = rh * 16 + kg * 4 + reg;
            const size_t grow = (size_t)row0 + r;
            float2 e0 = lnbuf[r][0], e1 = lnbuf[r][1];
            float s = e0.x + e1.x;
            float q = e0.y + e1.y;
            float mu = s * (1.f / DIM);
            float var = q * (1.f / DIM) - mu * mu;
            float rinv = rsqrtf(var + LN_EPS);
            if (grow < N_NODES) {
                #pragma unroll
                for (int n = 0; n < 4; ++n) {
                    float y = (vv[reg][n] - mu) * rinv * gg[n] + bb[n];
                    outb[grow * DIM + ch * 64 + n * 16 + cl] = f2bf(y);
                }
            }
        }
    } else {
        #pragma unroll
        for (int reg = 0; reg < 4; ++reg) {
            const int r = rh * 16 + kg * 4 + reg;
            const size_t grow = (size_t)row0 + r;
            if (grow < N_NODES) {
                #pragma unroll
                for (int n = 0; n < 4; ++n)
                    outf[grow * DIM + ch * 64 + n * 16 + cl] = acc[n][reg] + bias[n];
            }
        }
    }
}

// ================= launch =================

static inline size_t align256(size_t x) { return (x + 255) & ~(size_t)255; }

extern "C" void kernel_launch(void* const* d_in, const int* in_sizes, int n_in,
                              void* d_out, int out_size, void* d_ws, size_t ws_size,
                              hipStream_t stream) {
    const float* in_feat = (const float*)d_in[0];
    const int*   ei      = (const int*)d_in[1];
    const float* Wrel    = (const float*)d_in[2];
    const float* brel    = (const float*)d_in[3];
    const float* Wroot   = (const float*)d_in[4];
    const float* gamma   = (const float*)d_in[5];
    const float* beta    = (const float*)d_in[6];
    float* out = (float*)d_out;

    char* ws = (char*)d_ws;
    size_t off = 0;
    int* col = (int*)(ws + off);        off = align256(off + (size_t)COL_CAP * 4);
    int2* pairs = (int2*)(ws + off);    off = align256(off + (size_t)N_BKT * SEGCAP * 8);
    int* row_ptr = (int*)(ws + off);    off = align256(off + (size_t)(N_PAD + 2) * 4);
    int* gcur = (int*)(ws + off);       off = align256(off + (size_t)N_BKT * 4);
    int* bpad = (int*)(ws + off);       off = align256(off + (size_t)N_BKT * 4);
    int* bpadstart = (int*)(ws + off);  off = align256(off + (size_t)(N_BKT + 1) * 4);
    ushort* x0 = (ushort*)(ws + off);   off = align256(off + (size_t)N_PAD * DIM * 2);
    ushort* hA = (ushort*)(ws + off);   off = align256(off + (size_t)N_PAD * DIM * 2);
    ushort* hB = (ushort*)(ws + off);   off = align256(off + (size_t)N_PAD * DIM * 2);
    ushort* Wp = (ushort*)(ws + off);   off = align256(off + (size_t)4 * 2 * 128 * 128 * 2);
    (void)ws_size; (void)in_sizes; (void)n_in; (void)out_size;

    const int* src = ei;
    const int* dst = ei + N_EDGES;

    // CSR build: segmented scatter -> per-bucket degree/scan -> fill (padded x16)
    hipMemsetAsync(gcur, 0, (size_t)N_BKT * 4, stream);
    bscatter_kernel<<<NBLK, 256, 0, stream>>>(src, dst, gcur, pairs);
    ndeg_kernel<<<N_BKT, 256, 0, stream>>>(pairs, gcur, row_ptr, bpad);
    pscan_kernel<<<1, 256, 0, stream>>>(bpad, bpadstart);
    addbase_kernel<<<(N_PAD + 1 + 255) / 256, 256, 0, stream>>>(row_ptr, bpadstart);
    bfill_kernel<<<N_BKT, 256, 0, stream>>>(pairs, gcur, row_ptr, col);

    // merged prep: prepack + padzero + cvt (one launch)
    prep_kernel<<<66 + (N_NODES * DIM) / (4 * 256), 256, 0, stream>>>(
        in_feat, x0, Wrel, Wroot, Wp,
        (uint4*)(x0 + (size_t)N_NODES * DIM),
        (uint4*)(hA + (size_t)N_NODES * DIM),
        (uint4*)(hB + (size_t)N_NODES * DIM));

    const int grid = N_PAD / 32;   // 3126

    // layer 0 (no residual)
    fused_kernel<0><<<grid, 256, 0, stream>>>(x0, row_ptr, col, Wp, brel, gamma, beta, hA, nullptr);
    // layer 1 (residual folded into WrootP)
    fused_kernel<0><<<grid, 256, 0, stream>>>(hA, row_ptr, col, Wp + 32768, brel + DIM, gamma, beta, hB, nullptr);
    // layer 2 (residual folded into WrootP)
    fused_kernel<0><<<grid, 256, 0, stream>>>(hB, row_ptr, col, Wp + 2 * 32768, brel + 2 * DIM, gamma, beta, hA, nullptr);
    // layer 3 (plain conv, f32 output)
    fused_kernel<2><<<grid, 256, 0, stream>>>(hA, row_ptr, col, Wp + 3 * 32768, brel + 3 * DIM, gamma, beta, nullptr, out);
}